// Round 3
// baseline (209.854 us; speedup 1.0000x reference)
//
#include <hip/hip_runtime.h>
#include <math.h>

#define NN 2048
#define TT 1024
#define EPSF 1e-8f

#define BLOCK    256
#define GRID     2048
#define NPAIR    (NN * TT / 2)          // 1,048,576 row-pairs
#define NTHREADS (GRID * BLOCK)         // 524,288
#define PITER    (NPAIR / NTHREADS)     // exactly 2
#define PAIRS_PER_N (TT / 2)            // 512

struct Quat { float w, x, y, z; };

__device__ inline Quat qmul(const Quat a, const Quat b) {
    Quat r;
    r.w = a.w * b.w - a.x * b.x - a.y * b.y - a.z * b.z;
    r.x = a.w * b.x + a.x * b.w + a.y * b.z - a.z * b.y;
    r.y = a.w * b.y - a.x * b.z + a.y * b.w + a.z * b.x;
    r.z = a.w * b.z + a.x * b.y - a.y * b.x + a.z * b.w;
    return r;
}

__device__ inline Quat qconj(const Quat q) {
    Quat r; r.w = q.w; r.x = -q.x; r.y = -q.y; r.z = -q.z; return r;
}

__device__ inline Quat qexp3(float vx, float vy, float vz) {
    float n = fmaxf(sqrtf(vx * vx + vy * vy + vz * vz), EPSF);
    float s = __sinf(n) / n;
    Quat r;
    r.w = __cosf(n);
    r.x = s * vx; r.y = s * vy; r.z = s * vz;
    return r;
}

__device__ inline void qlog3(const Quat q, float& ox, float& oy, float& oz) {
    float n = fmaxf(sqrtf(q.x * q.x + q.y * q.y + q.z * q.z), EPSF);
    float c = fminf(fmaxf(q.w, -1.0f), 1.0f);
    float s = acosf(c) / n;
    ox = q.x * s; oy = q.y * s; oz = q.z * s;
}

__device__ inline float waveReduceF(float v) {
    #pragma unroll
    for (int o = 32; o > 0; o >>= 1) v += __shfl_down(v, o);
    return v;
}

__device__ inline double waveReduceD(double v) {
    #pragma unroll
    for (int o = 32; o > 0; o >>= 1) v += __shfl_down(v, o);
    return v;
}

// Computes the vo+imu pair terms for one row (given its row and neighbor data).
// row pred: pa[6], targ: ga[6]; neighbor pred: pb[6], targ: gb[6]
// qR = qexp(row targ rot) (precomputed), qN = qexp(neighbor targ rot)
// accel/vel/angvel/ts from imu row; tsN = neighbor ts.
__device__ inline void pair_terms(
    const float pa[6], const float pb[6], const float ga[6], const float gb[6],
    const Quat qR, const Quat qN,
    float a0, float a1, float a2, float v0, float v1, float v2,
    float w0, float w1, float w2, float ts0, float ts1,
    float& s2, float& s3, float& s4, float& s5)
{
    float pv0 = pb[0] - pa[0], pv1 = pb[1] - pa[1], pv2 = pb[2] - pa[2];
    float pv3 = pb[3] - pa[3], pv4 = pb[4] - pa[4], pv5 = pb[5] - pa[5];
    float tv0 = gb[0] - ga[0], tv1 = gb[1] - ga[1], tv2 = gb[2] - ga[2];
    float tv3 = gb[3] - ga[3], tv4 = gb[4] - ga[4], tv5 = gb[5] - ga[5];

    s2 += fabsf(pv0 - tv0) + fabsf(pv1 - tv1) + fabsf(pv2 - tv2);
    s3 += fabsf(pv3 - tv3) + fabsf(pv4 - tv4) + fabsf(pv5 - tv5);

    Quat qRi = qconj(qR);
    Quat r01 = qmul(qRi, qN);
    float tq0, tq1, tq2;
    qlog3(r01, tq0, tq1, tq2);            // targ_imu_q

    float dt = (ts1 - ts0) * 1e-9f;
    float hdt2 = 0.5f * dt * dt;
    float it0 = v0 * dt + a0 * hdt2;
    float it1 = v1 * dt + a1 * hdt2;
    float it2 = v2 * dt + a2 * hdt2;
    s4 += fabsf(pv0 - it0) + fabsf(pv1 - it1) + fabsf(pv2 - it2);

    float wn = fmaxf(sqrtf(w0 * w0 + w1 * w1 + w2 * w2), EPSF);
    float half = 0.5f * wn * dt;
    float sd = __sinf(half) / wn;
    Quat dq; dq.w = __cosf(half); dq.x = w0 * sd; dq.y = w1 * sd; dq.z = w2 * sd;
    Quat nq = qmul(qR, dq);               // new_q
    Quat m  = qmul(qRi, nq);
    float io0, io1, io2;
    qlog3(m, io0, io1, io2);              // imu_ori_shift
    s5 += fabsf(tq0 - io0) + fabsf(tq1 - io1) + fabsf(tq2 - io2);
}

__global__ __launch_bounds__(BLOCK) void loss_main(
    const float* __restrict__ pred, const float* __restrict__ targ,
    const float* __restrict__ imu, float* __restrict__ partial)
{
    float s0 = 0.f, s1 = 0.f, s2 = 0.f, s3 = 0.f, s4 = 0.f, s5 = 0.f;
    const int base = blockIdx.x * BLOCK + threadIdx.x;

    #pragma unroll
    for (int k = 0; k < PITER; ++k) {
        const int u = base + k * NTHREADS;         // pair index
        const int tp = u & (PAIRS_PER_N - 1);      // pair-in-sequence

        const float4* p4 = reinterpret_cast<const float4*>(pred) + (size_t)u * 3;
        const float4* g4 = reinterpret_cast<const float4*>(targ) + (size_t)u * 3;
        const float4* i4 = reinterpret_cast<const float4*>(imu)  + (size_t)u * 5;

        float4 P0 = p4[0], P1 = p4[1], P2 = p4[2];
        float4 G0 = g4[0], G1 = g4[1], G2 = g4[2];
        float4 I0 = i4[0], I1 = i4[1], I2 = i4[2], I3 = i4[3], I4 = i4[4];

        // rows: A = pair floats 0..5, B = pair floats 6..11
        float pA[6] = {P0.x, P0.y, P0.z, P0.w, P1.x, P1.y};
        float pB[6] = {P1.z, P1.w, P2.x, P2.y, P2.z, P2.w};
        float gA[6] = {G0.x, G0.y, G0.z, G0.w, G1.x, G1.y};
        float gB[6] = {G1.z, G1.w, G2.x, G2.y, G2.z, G2.w};

        // abs_loss partials
        s0 += fabsf(pA[0]-gA[0]) + fabsf(pA[1]-gA[1]) + fabsf(pA[2]-gA[2])
            + fabsf(pB[0]-gB[0]) + fabsf(pB[1]-gB[1]) + fabsf(pB[2]-gB[2]);
        s1 += fabsf(pA[3]-gA[3]) + fabsf(pA[4]-gA[4]) + fabsf(pA[5]-gA[5])
            + fabsf(pB[3]-gB[3]) + fabsf(pB[4]-gB[4]) + fabsf(pB[5]-gB[5]);

        // quaternion exps for the pair's two targ rows (qB shared between rows)
        Quat qA = qexp3(gA[3], gA[4], gA[5]);
        Quat qB = qexp3(gB[3], gB[4], gB[5]);

        // imu row A: accel im0-2, vel im3-5, angvel im6-8, ts im9
        // imu row B: accel im10-12, vel im13-15, angvel im16-18, ts im19
        float tsA = I2.y, tsB = I4.w;

        // row A -> row B (always valid: A has even t <= 1022)
        pair_terms(pA, pB, gA, gB, qA, qB,
                   I0.x, I0.y, I0.z,      // accel A
                   I0.w, I1.x, I1.y,      // vel A
                   I1.z, I1.w, I2.x,      // angvel A
                   tsA, tsB, s2, s3, s4, s5);

        // row B -> row C (next pair's first row), skip at sequence end
        if (tp != PAIRS_PER_N - 1) {
            float4 P3 = p4[3];
            float2 PF = reinterpret_cast<const float2*>(pred)[(size_t)u * 6 + 8];
            float4 G3 = g4[3];
            float2 GF = reinterpret_cast<const float2*>(targ)[(size_t)u * 6 + 8];
            float tsC = imu[(size_t)u * 20 + 29];

            float pC[6] = {P3.x, P3.y, P3.z, P3.w, PF.x, PF.y};
            float gC[6] = {G3.x, G3.y, G3.z, G3.w, GF.x, GF.y};

            Quat qC = qexp3(gC[3], gC[4], gC[5]);

            pair_terms(pB, pC, gB, gC, qB, qC,
                       I2.z, I2.w, I3.x,  // accel B
                       I3.y, I3.z, I3.w,  // vel B
                       I4.x, I4.y, I4.z,  // angvel B
                       tsB, tsC, s2, s3, s4, s5);
        }
    }

    // block reduction: wave shuffle -> LDS -> per-block partial store (NO atomics)
    s0 = waveReduceF(s0); s1 = waveReduceF(s1); s2 = waveReduceF(s2);
    s3 = waveReduceF(s3); s4 = waveReduceF(s4); s5 = waveReduceF(s5);

    __shared__ float red[4][6];
    const int lane = threadIdx.x & 63;
    const int wid  = threadIdx.x >> 6;
    if (lane == 0) {
        red[wid][0] = s0; red[wid][1] = s1; red[wid][2] = s2;
        red[wid][3] = s3; red[wid][4] = s4; red[wid][5] = s5;
    }
    __syncthreads();
    if (threadIdx.x < 6) {
        const int c = threadIdx.x;
        partial[(size_t)blockIdx.x * 6 + c] = red[0][c] + red[1][c] + red[2][c] + red[3][c];
    }
}

__global__ __launch_bounds__(256) void loss_finalize(
    const float* __restrict__ partial,
    const float* __restrict__ sax, const float* __restrict__ saq,
    const float* __restrict__ srx, const float* __restrict__ srq,
    float* __restrict__ out)
{
    double t0 = 0, t1 = 0, t2 = 0, t3 = 0, t4 = 0, t5 = 0;
    for (int r = threadIdx.x; r < GRID; r += 256) {
        const float* p = partial + (size_t)r * 6;
        t0 += p[0]; t1 += p[1]; t2 += p[2];
        t3 += p[3]; t4 += p[4]; t5 += p[5];
    }
    t0 = waveReduceD(t0); t1 = waveReduceD(t1); t2 = waveReduceD(t2);
    t3 = waveReduceD(t3); t4 = waveReduceD(t4); t5 = waveReduceD(t5);

    __shared__ double red[4][6];
    const int lane = threadIdx.x & 63;
    const int wid  = threadIdx.x >> 6;
    if (lane == 0) {
        red[wid][0] = t0; red[wid][1] = t1; red[wid][2] = t2;
        red[wid][3] = t3; red[wid][4] = t4; red[wid][5] = t5;
    }
    __syncthreads();
    if (threadIdx.x == 0) {
        double a0 = 0, a1 = 0, a2 = 0, a3 = 0, a4 = 0, a5 = 0;
        #pragma unroll
        for (int w = 0; w < 4; ++w) {
            a0 += red[w][0]; a1 += red[w][1]; a2 += red[w][2];
            a3 += red[w][3]; a4 += red[w][4]; a5 += red[w][5];
        }
        const double inv_abs = 1.0 / ((double)NN * TT * 3);
        const double inv_vo  = 1.0 / ((double)NN * (TT - 1) * 3);
        float A = (float)(a0 * inv_abs);
        float B = (float)(a1 * inv_abs);
        float C = (float)(a2 * inv_vo);
        float D = (float)(a3 * inv_vo);
        float E = (float)(a4 * inv_vo);
        float F = (float)(a5 * inv_vo);
        float sx = sax[0], sq = saq[0], rx = srx[0], rq = srq[0];
        out[0] = expf(-sx) * A + sx + expf(-sq) * B + sq
               + expf(-rx) * (C + E) + 2.0f * rx
               + expf(-rq) * (D + F) + 2.0f * rq;
    }
}

extern "C" void kernel_launch(void* const* d_in, const int* in_sizes, int n_in,
                              void* d_out, int out_size, void* d_ws, size_t ws_size,
                              hipStream_t stream) {
    const float* pred = (const float*)d_in[0];
    const float* targ = (const float*)d_in[1];
    const float* imu  = (const float*)d_in[2];
    const float* sax  = (const float*)d_in[3];
    const float* saq  = (const float*)d_in[4];
    const float* srx  = (const float*)d_in[5];
    const float* srq  = (const float*)d_in[6];
    float* out = (float*)d_out;
    float* partial = (float*)d_ws;   // GRID * 6 floats = 48 KB

    loss_main<<<GRID, BLOCK, 0, stream>>>(pred, targ, imu, partial);
    loss_finalize<<<1, 256, 0, stream>>>(partial, sax, saq, srx, srq, out);
}

// Round 4
// 209.694 us; speedup vs baseline: 1.0008x; 1.0008x over previous
//
#include <hip/hip_runtime.h>
#include <math.h>

#define NN 2048
#define TT 1024
#define EPSF 1e-8f
#define BLOCK 256
#define HALF 512                  // rows per block
#define NBLK (NN * 2)             // 4096 blocks

struct Quat { float w, x, y, z; };

__device__ inline float fsqrt_f(float x) { return __builtin_amdgcn_sqrtf(x); }
__device__ inline float frcp_f(float x)  { return __builtin_amdgcn_rcpf(x); }

// max abs error ~6.8e-5 rad (Abramowitz-Stegun 4.4.45 + reflection)
__device__ inline float acos_fast(float x) {
    float ax = fabsf(x);
    float p = fmaf(ax, -0.0187293f, 0.0742610f);
    p = fmaf(ax, p, -0.2121144f);
    p = fmaf(ax, p, 1.5707288f);
    float r = fsqrt_f(1.0f - ax) * p;
    return x >= 0.0f ? r : 3.14159274f - r;
}

__device__ inline Quat qmul(const Quat a, const Quat b) {
    Quat r;
    r.w = a.w * b.w - a.x * b.x - a.y * b.y - a.z * b.z;
    r.x = a.w * b.x + a.x * b.w + a.y * b.z - a.z * b.y;
    r.y = a.w * b.y - a.x * b.z + a.y * b.w + a.z * b.x;
    r.z = a.w * b.z + a.x * b.y - a.y * b.x + a.z * b.w;
    return r;
}

__device__ inline Quat qconj(const Quat q) {
    Quat r; r.w = q.w; r.x = -q.x; r.y = -q.y; r.z = -q.z; return r;
}

__device__ inline Quat qexp3(float vx, float vy, float vz) {
    float ss = fmaf(vx, vx, fmaf(vy, vy, vz * vz));
    float n = fmaxf(fsqrt_f(ss), EPSF);
    float s = __sinf(n) * frcp_f(n);
    Quat r; r.w = __cosf(n); r.x = s * vx; r.y = s * vy; r.z = s * vz;
    return r;
}

__device__ inline void qlog3(const Quat q, float& ox, float& oy, float& oz) {
    float ss = fmaf(q.x, q.x, fmaf(q.y, q.y, q.z * q.z));
    float n = fmaxf(fsqrt_f(ss), EPSF);
    float c = fminf(fmaxf(q.w, -1.0f), 1.0f);
    float s = acos_fast(c) * frcp_f(n);
    ox = q.x * s; oy = q.y * s; oz = q.z * s;
}

__device__ inline float waveReduceF(float v) {
    #pragma unroll
    for (int o = 32; o > 0; o >>= 1) v += __shfl_down(v, o);
    return v;
}

__device__ inline double waveReduceD(double v) {
    #pragma unroll
    for (int o = 32; o > 0; o >>= 1) v += __shfl_down(v, o);
    return v;
}

// vo + imu terms for one row->neighbor step.
// NOTE: imu_ori_shift = qlog(qmult(qinv(q0), qmult(q0, dq))) = qlog(|q0|^2 dq)
// and since q0 is unit and dq = [cos(.5*wn*dt), w/wn*sin(.5*wn*dt)], this is
// exactly 0.5*dt*w (up to f32 rounding ~1e-7) -- the dq chain collapses.
__device__ inline void pair_terms(
    const float* pa, const float* pb, const float* ga, const float* gb,
    const Quat qR, const Quat qN,
    float a0, float a1, float a2, float v0, float v1, float v2,
    float w0, float w1, float w2, float ts0, float ts1,
    float& s2, float& s3, float& s4, float& s5)
{
    float pv0 = pb[0] - pa[0], pv1 = pb[1] - pa[1], pv2 = pb[2] - pa[2];
    float pv3 = pb[3] - pa[3], pv4 = pb[4] - pa[4], pv5 = pb[5] - pa[5];
    float tv0 = gb[0] - ga[0], tv1 = gb[1] - ga[1], tv2 = gb[2] - ga[2];
    float tv3 = gb[3] - ga[3], tv4 = gb[4] - ga[4], tv5 = gb[5] - ga[5];

    s2 += fabsf(pv0 - tv0) + fabsf(pv1 - tv1) + fabsf(pv2 - tv2);
    s3 += fabsf(pv3 - tv3) + fabsf(pv4 - tv4) + fabsf(pv5 - tv5);

    Quat r01 = qmul(qconj(qR), qN);
    float tq0, tq1, tq2;
    qlog3(r01, tq0, tq1, tq2);            // targ_imu_q

    float dt = (ts1 - ts0) * 1e-9f;
    float hdt2 = 0.5f * dt * dt;
    float it0 = fmaf(v0, dt, a0 * hdt2);
    float it1 = fmaf(v1, dt, a1 * hdt2);
    float it2 = fmaf(v2, dt, a2 * hdt2);
    s4 += fabsf(pv0 - it0) + fabsf(pv1 - it1) + fabsf(pv2 - it2);

    float kk = 0.5f * dt;                 // imu_ori_shift = kk * w
    s5 += fabsf(tq0 - kk * w0) + fabsf(tq1 - kk * w1) + fabsf(tq2 - kk * w2);
}

__global__ __launch_bounds__(BLOCK) void loss_main(
    const float* __restrict__ pred, const float* __restrict__ targ,
    const float* __restrict__ imu, float* __restrict__ partial)
{
    __shared__ __align__(16) float sp[HALF * 6];    // 12 KB
    __shared__ __align__(16) float sg[HALF * 6];    // 12 KB
    __shared__ __align__(16) float si[HALF * 10];   // 20 KB
    __shared__ float nbr[13];
    __shared__ float red[4][6];

    const int tid = threadIdx.x;
    const int bid = blockIdx.x;
    const int n = bid >> 1, h = bid & 1;

    const float* pbase = pred + ((size_t)n * TT + (size_t)h * HALF) * 6;
    const float* gbase = targ + ((size_t)n * TT + (size_t)h * HALF) * 6;
    const float* ibase = imu  + ((size_t)n * TT + (size_t)h * HALF) * 10;

    // neighbor row (r0+512): only exists for h==0 (h==1 would cross sequences)
    if (h == 0) {
        if (tid < 6)        nbr[tid] = pbase[HALF * 6 + tid];
        else if (tid < 12)  nbr[tid] = gbase[HALF * 6 + (tid - 6)];
        else if (tid == 12) nbr[12]  = ibase[HALF * 10 + 9];
    }

    // perfectly-coalesced staging: stride-1 float4, 16 lines/instruction
    const float4* pg4 = reinterpret_cast<const float4*>(pbase);
    const float4* gg4 = reinterpret_cast<const float4*>(gbase);
    const float4* ig4 = reinterpret_cast<const float4*>(ibase);
    float4* sp4 = reinterpret_cast<float4*>(sp);
    float4* sg4 = reinterpret_cast<float4*>(sg);
    float4* si4 = reinterpret_cast<float4*>(si);
    #pragma unroll
    for (int k = 0; k < 3; ++k) sp4[tid + k * BLOCK] = pg4[tid + k * BLOCK];
    #pragma unroll
    for (int k = 0; k < 3; ++k) sg4[tid + k * BLOCK] = gg4[tid + k * BLOCK];
    #pragma unroll
    for (int k = 0; k < 5; ++k) si4[tid + k * BLOCK] = ig4[tid + k * BLOCK];

    __syncthreads();

    float s0 = 0.f, s1 = 0.f, s2 = 0.f, s3 = 0.f, s4 = 0.f, s5 = 0.f;

    // thread tid owns local rows 2*tid (A) and 2*tid+1 (B)
    const float2* P = reinterpret_cast<const float2*>(sp + tid * 12);
    const float2* G = reinterpret_cast<const float2*>(sg + tid * 12);
    const float2* I = reinterpret_cast<const float2*>(si + tid * 20);

    float2 P0 = P[0], P1 = P[1], P2 = P[2], P3 = P[3], P4 = P[4], P5 = P[5];
    float2 G0 = G[0], G1 = G[1], G2 = G[2], G3 = G[3], G4 = G[4], G5 = G[5];
    float2 I0 = I[0], I1 = I[1], I2 = I[2], I3 = I[3], I4 = I[4];
    float2 I5 = I[5], I6 = I[6], I7 = I[7], I8 = I[8], I9 = I[9];

    float pA[6] = {P0.x, P0.y, P1.x, P1.y, P2.x, P2.y};
    float pB[6] = {P3.x, P3.y, P4.x, P4.y, P5.x, P5.y};
    float gA[6] = {G0.x, G0.y, G1.x, G1.y, G2.x, G2.y};
    float gB[6] = {G3.x, G3.y, G4.x, G4.y, G5.x, G5.y};

    s0 += fabsf(pA[0]-gA[0]) + fabsf(pA[1]-gA[1]) + fabsf(pA[2]-gA[2])
        + fabsf(pB[0]-gB[0]) + fabsf(pB[1]-gB[1]) + fabsf(pB[2]-gB[2]);
    s1 += fabsf(pA[3]-gA[3]) + fabsf(pA[4]-gA[4]) + fabsf(pA[5]-gA[5])
        + fabsf(pB[3]-gB[3]) + fabsf(pB[4]-gB[4]) + fabsf(pB[5]-gB[5]);

    Quat qA = qexp3(gA[3], gA[4], gA[5]);
    Quat qB = qexp3(gB[3], gB[4], gB[5]);

    float tsA = I4.y, tsB = I9.y;

    // A -> B (always valid: global t of A is even, <= 1022)
    pair_terms(pA, pB, gA, gB, qA, qB,
               I0.x, I0.y, I1.x,    // accel A
               I1.y, I2.x, I2.y,    // vel A
               I3.x, I3.y, I4.x,    // angvel A
               tsA, tsB, s2, s3, s4, s5);

    // B -> C (C = next pair's first row; last pair of h==1 has no C)
    const bool lastPair = (tid == BLOCK - 1);
    if (!(h == 1 && lastPair)) {
        float pC[6], gC[6], tsC;
        if (!lastPair) {
            const float2* Pn = reinterpret_cast<const float2*>(sp + tid * 12 + 12);
            const float2* Gn = reinterpret_cast<const float2*>(sg + tid * 12 + 12);
            float2 a = Pn[0], b = Pn[1], c = Pn[2];
            float2 d = Gn[0], e = Gn[1], f = Gn[2];
            pC[0]=a.x; pC[1]=a.y; pC[2]=b.x; pC[3]=b.y; pC[4]=c.x; pC[5]=c.y;
            gC[0]=d.x; gC[1]=d.y; gC[2]=e.x; gC[3]=e.y; gC[4]=f.x; gC[5]=f.y;
            tsC = si[tid * 20 + 29];
        } else {
            pC[0]=nbr[0]; pC[1]=nbr[1]; pC[2]=nbr[2]; pC[3]=nbr[3]; pC[4]=nbr[4]; pC[5]=nbr[5];
            gC[0]=nbr[6]; gC[1]=nbr[7]; gC[2]=nbr[8]; gC[3]=nbr[9]; gC[4]=nbr[10]; gC[5]=nbr[11];
            tsC = nbr[12];
        }
        Quat qC = qexp3(gC[3], gC[4], gC[5]);
        pair_terms(pB, pC, gB, gC, qB, qC,
                   I5.x, I5.y, I6.x,    // accel B
                   I6.y, I7.x, I7.y,    // vel B
                   I8.x, I8.y, I9.x,    // angvel B
                   tsB, tsC, s2, s3, s4, s5);
    }

    // block reduction: wave shuffle -> LDS -> per-block partial store
    s0 = waveReduceF(s0); s1 = waveReduceF(s1); s2 = waveReduceF(s2);
    s3 = waveReduceF(s3); s4 = waveReduceF(s4); s5 = waveReduceF(s5);

    const int lane = tid & 63;
    const int wid  = tid >> 6;
    if (lane == 0) {
        red[wid][0] = s0; red[wid][1] = s1; red[wid][2] = s2;
        red[wid][3] = s3; red[wid][4] = s4; red[wid][5] = s5;
    }
    __syncthreads();
    if (tid < 6) {
        const int c = tid;
        partial[(size_t)bid * 6 + c] = red[0][c] + red[1][c] + red[2][c] + red[3][c];
    }
}

__global__ __launch_bounds__(256) void loss_finalize(
    const float* __restrict__ partial,
    const float* __restrict__ sax, const float* __restrict__ saq,
    const float* __restrict__ srx, const float* __restrict__ srq,
    float* __restrict__ out)
{
    double t0 = 0, t1 = 0, t2 = 0, t3 = 0, t4 = 0, t5 = 0;
    for (int r = threadIdx.x; r < NBLK; r += 256) {
        const float* p = partial + (size_t)r * 6;
        t0 += p[0]; t1 += p[1]; t2 += p[2];
        t3 += p[3]; t4 += p[4]; t5 += p[5];
    }
    t0 = waveReduceD(t0); t1 = waveReduceD(t1); t2 = waveReduceD(t2);
    t3 = waveReduceD(t3); t4 = waveReduceD(t4); t5 = waveReduceD(t5);

    __shared__ double red[4][6];
    const int lane = threadIdx.x & 63;
    const int wid  = threadIdx.x >> 6;
    if (lane == 0) {
        red[wid][0] = t0; red[wid][1] = t1; red[wid][2] = t2;
        red[wid][3] = t3; red[wid][4] = t4; red[wid][5] = t5;
    }
    __syncthreads();
    if (threadIdx.x == 0) {
        double a0 = 0, a1 = 0, a2 = 0, a3 = 0, a4 = 0, a5 = 0;
        #pragma unroll
        for (int w = 0; w < 4; ++w) {
            a0 += red[w][0]; a1 += red[w][1]; a2 += red[w][2];
            a3 += red[w][3]; a4 += red[w][4]; a5 += red[w][5];
        }
        const double inv_abs = 1.0 / ((double)NN * TT * 3);
        const double inv_vo  = 1.0 / ((double)NN * (TT - 1) * 3);
        float A = (float)(a0 * inv_abs);
        float B = (float)(a1 * inv_abs);
        float C = (float)(a2 * inv_vo);
        float D = (float)(a3 * inv_vo);
        float E = (float)(a4 * inv_vo);
        float F = (float)(a5 * inv_vo);
        float sx = sax[0], sq = saq[0], rx = srx[0], rq = srq[0];
        out[0] = expf(-sx) * A + sx + expf(-sq) * B + sq
               + expf(-rx) * (C + E) + 2.0f * rx
               + expf(-rq) * (D + F) + 2.0f * rq;
    }
}

extern "C" void kernel_launch(void* const* d_in, const int* in_sizes, int n_in,
                              void* d_out, int out_size, void* d_ws, size_t ws_size,
                              hipStream_t stream) {
    const float* pred = (const float*)d_in[0];
    const float* targ = (const float*)d_in[1];
    const float* imu  = (const float*)d_in[2];
    const float* sax  = (const float*)d_in[3];
    const float* saq  = (const float*)d_in[4];
    const float* srx  = (const float*)d_in[5];
    const float* srq  = (const float*)d_in[6];
    float* out = (float*)d_out;
    float* partial = (float*)d_ws;   // NBLK * 6 floats = 96 KB

    loss_main<<<NBLK, BLOCK, 0, stream>>>(pred, targ, imu, partial);
    loss_finalize<<<1, 256, 0, stream>>>(partial, sax, saq, srx, srq, out);
}

// Round 5
// 206.394 us; speedup vs baseline: 1.0168x; 1.0160x over previous
//
#include <hip/hip_runtime.h>
#include <math.h>

#define NN 2048
#define TT 1024
#define EPSF 1e-8f

#define NPAIR (NN * TT / 2)              // 1,048,576 row-pairs
#define BLOCK 256
#define WPB   (BLOCK / 64)               // 4 waves per block
#define NWAVE ((NPAIR + 62) / 63)        // 16,645 waves (63 pairs each)
#define NBLK  ((NWAVE + WPB - 1) / WPB)  // 4,162 blocks

struct Quat { float w, x, y, z; };

__device__ inline float fsqrt_f(float x) { return __builtin_amdgcn_sqrtf(x); }
__device__ inline float frcp_f(float x)  { return __builtin_amdgcn_rcpf(x); }

// max abs error ~6.8e-5 rad (Abramowitz-Stegun 4.4.45 + reflection)
__device__ inline float acos_fast(float x) {
    float ax = fabsf(x);
    float p = fmaf(ax, -0.0187293f, 0.0742610f);
    p = fmaf(ax, p, -0.2121144f);
    p = fmaf(ax, p, 1.5707288f);
    float r = fsqrt_f(1.0f - ax) * p;
    return x >= 0.0f ? r : 3.14159274f - r;
}

__device__ inline Quat qmul(const Quat a, const Quat b) {
    Quat r;
    r.w = a.w * b.w - a.x * b.x - a.y * b.y - a.z * b.z;
    r.x = a.w * b.x + a.x * b.w + a.y * b.z - a.z * b.y;
    r.y = a.w * b.y - a.x * b.z + a.y * b.w + a.z * b.x;
    r.z = a.w * b.z + a.x * b.y - a.y * b.x + a.z * b.w;
    return r;
}

__device__ inline Quat qconj(const Quat q) {
    Quat r; r.w = q.w; r.x = -q.x; r.y = -q.y; r.z = -q.z; return r;
}

__device__ inline Quat qexp3(float vx, float vy, float vz) {
    float ss = fmaf(vx, vx, fmaf(vy, vy, vz * vz));
    float n = fmaxf(fsqrt_f(ss), EPSF);
    float s = __sinf(n) * frcp_f(n);
    Quat r; r.w = __cosf(n); r.x = s * vx; r.y = s * vy; r.z = s * vz;
    return r;
}

__device__ inline void qlog3(const Quat q, float& ox, float& oy, float& oz) {
    float ss = fmaf(q.x, q.x, fmaf(q.y, q.y, q.z * q.z));
    float n = fmaxf(fsqrt_f(ss), EPSF);
    float c = fminf(fmaxf(q.w, -1.0f), 1.0f);
    float s = acos_fast(c) * frcp_f(n);
    ox = q.x * s; oy = q.y * s; oz = q.z * s;
}

__device__ inline float waveReduceF(float v) {
    #pragma unroll
    for (int o = 32; o > 0; o >>= 1) v += __shfl_down(v, o);
    return v;
}

__device__ inline double waveReduceD(double v) {
    #pragma unroll
    for (int o = 32; o > 0; o >>= 1) v += __shfl_down(v, o);
    return v;
}

// vo + imu terms for one row->neighbor step.
// imu_ori_shift = qlog(qmult(qinv(q0), qmult(q0, dq))) = qlog(dq) = 0.5*dt*w
// exactly (q0 unit), so the dq sin/cos chain collapses to one multiply.
__device__ inline void pair_terms(
    const float* pa, const float* pb, const float* ga, const float* gb,
    const Quat qR, const Quat qN,
    float a0, float a1, float a2, float v0, float v1, float v2,
    float w0, float w1, float w2, float ts0, float ts1,
    float& s2, float& s3, float& s4, float& s5)
{
    float pv0 = pb[0] - pa[0], pv1 = pb[1] - pa[1], pv2 = pb[2] - pa[2];
    float pv3 = pb[3] - pa[3], pv4 = pb[4] - pa[4], pv5 = pb[5] - pa[5];
    float tv0 = gb[0] - ga[0], tv1 = gb[1] - ga[1], tv2 = gb[2] - ga[2];
    float tv3 = gb[3] - ga[3], tv4 = gb[4] - ga[4], tv5 = gb[5] - ga[5];

    s2 += fabsf(pv0 - tv0) + fabsf(pv1 - tv1) + fabsf(pv2 - tv2);
    s3 += fabsf(pv3 - tv3) + fabsf(pv4 - tv4) + fabsf(pv5 - tv5);

    Quat r01 = qmul(qconj(qR), qN);
    float tq0, tq1, tq2;
    qlog3(r01, tq0, tq1, tq2);            // targ_imu_q

    float dt = (ts1 - ts0) * 1e-9f;
    float hdt2 = 0.5f * dt * dt;
    float it0 = fmaf(v0, dt, a0 * hdt2);
    float it1 = fmaf(v1, dt, a1 * hdt2);
    float it2 = fmaf(v2, dt, a2 * hdt2);
    s4 += fabsf(pv0 - it0) + fabsf(pv1 - it1) + fabsf(pv2 - it2);

    float kk = 0.5f * dt;                 // imu_ori_shift = kk * w
    s5 += fabsf(tq0 - kk * w0) + fabsf(tq1 - kk * w1) + fabsf(tq2 - kk * w2);
}

__global__ __launch_bounds__(BLOCK) void loss_main(
    const float* __restrict__ pred, const float* __restrict__ targ,
    const float* __restrict__ imu, float* __restrict__ partial)
{
    const int tid  = threadIdx.x;
    const int lane = tid & 63;
    const int wid  = tid >> 6;

    // wave handles 63 pairs; lane 63 is shuffle-feed only (its pair == next
    // wave's lane-0 pair, so every pair is accumulated exactly once).
    const long wave = (long)blockIdx.x * WPB + wid;
    const long u    = wave * 63 + lane;
    const bool valid  = (u < NPAIR);
    const bool active = (lane < 63) && valid;
    const long uc = valid ? u : (NPAIR - 1);   // clamp OOB tail (loads only)

    const float4* p4 = reinterpret_cast<const float4*>(pred) + uc * 3;
    const float4* g4 = reinterpret_cast<const float4*>(targ) + uc * 3;
    const float4* i4 = reinterpret_cast<const float4*>(imu)  + uc * 5;

    float4 P0 = p4[0], P1 = p4[1], P2 = p4[2];
    float4 G0 = g4[0], G1 = g4[1], G2 = g4[2];
    float4 I0 = i4[0], I1 = i4[1], I2 = i4[2], I3 = i4[3], I4 = i4[4];

    // rows A (pair floats 0..5) and B (6..11)
    float pA[6] = {P0.x, P0.y, P0.z, P0.w, P1.x, P1.y};
    float pB[6] = {P1.z, P1.w, P2.x, P2.y, P2.z, P2.w};
    float gA[6] = {G0.x, G0.y, G0.z, G0.w, G1.x, G1.y};
    float gB[6] = {G1.z, G1.w, G2.x, G2.y, G2.z, G2.w};

    Quat qA = qexp3(gA[3], gA[4], gA[5]);
    Quat qB = qexp3(gB[3], gB[4], gB[5]);
    float tsA = I2.y, tsB = I4.w;

    // C row (next pair's A row) via in-register shuffle from lane+1
    float pC[6], gC[6];
    #pragma unroll
    for (int j = 0; j < 6; ++j) {
        pC[j] = __shfl_down(pA[j], 1);
        gC[j] = __shfl_down(gA[j], 1);
    }
    float tsC = __shfl_down(tsA, 1);
    Quat qC;
    qC.w = __shfl_down(qA.w, 1); qC.x = __shfl_down(qA.x, 1);
    qC.y = __shfl_down(qA.y, 1); qC.z = __shfl_down(qA.z, 1);

    float s0 = 0.f, s1 = 0.f, s2 = 0.f, s3 = 0.f, s4 = 0.f, s5 = 0.f;

    if (active) {
        s0 += fabsf(pA[0]-gA[0]) + fabsf(pA[1]-gA[1]) + fabsf(pA[2]-gA[2])
            + fabsf(pB[0]-gB[0]) + fabsf(pB[1]-gB[1]) + fabsf(pB[2]-gB[2]);
        s1 += fabsf(pA[3]-gA[3]) + fabsf(pA[4]-gA[4]) + fabsf(pA[5]-gA[5])
            + fabsf(pB[3]-gB[3]) + fabsf(pB[4]-gB[4]) + fabsf(pB[5]-gB[5]);

        // A -> B (within pair; never crosses a sequence)
        pair_terms(pA, pB, gA, gB, qA, qB,
                   I0.x, I0.y, I0.z,     // accel A
                   I0.w, I1.x, I1.y,     // vel A
                   I1.z, I1.w, I2.x,     // angvel A
                   tsA, tsB, s2, s3, s4, s5);

        // B -> C, skip for the last pair of each sequence (t == TT-1)
        if ((u & 511) != 511) {
            pair_terms(pB, pC, gB, gC, qB, qC,
                       I2.z, I2.w, I3.x, // accel B
                       I3.y, I3.z, I3.w, // vel B
                       I4.x, I4.y, I4.z, // angvel B
                       tsB, tsC, s2, s3, s4, s5);
        }
    }

    // block reduction: wave shuffle -> LDS -> per-block partial store
    s0 = waveReduceF(s0); s1 = waveReduceF(s1); s2 = waveReduceF(s2);
    s3 = waveReduceF(s3); s4 = waveReduceF(s4); s5 = waveReduceF(s5);

    __shared__ float red[WPB][6];
    if (lane == 0) {
        red[wid][0] = s0; red[wid][1] = s1; red[wid][2] = s2;
        red[wid][3] = s3; red[wid][4] = s4; red[wid][5] = s5;
    }
    __syncthreads();
    if (tid < 6) {
        const int c = tid;
        partial[(size_t)blockIdx.x * 6 + c] = red[0][c] + red[1][c] + red[2][c] + red[3][c];
    }
}

__global__ __launch_bounds__(256) void loss_finalize(
    const float* __restrict__ partial,
    const float* __restrict__ sax, const float* __restrict__ saq,
    const float* __restrict__ srx, const float* __restrict__ srq,
    float* __restrict__ out)
{
    double t0 = 0, t1 = 0, t2 = 0, t3 = 0, t4 = 0, t5 = 0;
    for (int r = threadIdx.x; r < NBLK; r += 256) {
        const float* p = partial + (size_t)r * 6;
        t0 += p[0]; t1 += p[1]; t2 += p[2];
        t3 += p[3]; t4 += p[4]; t5 += p[5];
    }
    t0 = waveReduceD(t0); t1 = waveReduceD(t1); t2 = waveReduceD(t2);
    t3 = waveReduceD(t3); t4 = waveReduceD(t4); t5 = waveReduceD(t5);

    __shared__ double red[4][6];
    const int lane = threadIdx.x & 63;
    const int wid  = threadIdx.x >> 6;
    if (lane == 0) {
        red[wid][0] = t0; red[wid][1] = t1; red[wid][2] = t2;
        red[wid][3] = t3; red[wid][4] = t4; red[wid][5] = t5;
    }
    __syncthreads();
    if (threadIdx.x == 0) {
        double a0 = 0, a1 = 0, a2 = 0, a3 = 0, a4 = 0, a5 = 0;
        #pragma unroll
        for (int w = 0; w < 4; ++w) {
            a0 += red[w][0]; a1 += red[w][1]; a2 += red[w][2];
            a3 += red[w][3]; a4 += red[w][4]; a5 += red[w][5];
        }
        const double inv_abs = 1.0 / ((double)NN * TT * 3);
        const double inv_vo  = 1.0 / ((double)NN * (TT - 1) * 3);
        float A = (float)(a0 * inv_abs);
        float B = (float)(a1 * inv_abs);
        float C = (float)(a2 * inv_vo);
        float D = (float)(a3 * inv_vo);
        float E = (float)(a4 * inv_vo);
        float F = (float)(a5 * inv_vo);
        float sx = sax[0], sq = saq[0], rx = srx[0], rq = srq[0];
        out[0] = expf(-sx) * A + sx + expf(-sq) * B + sq
               + expf(-rx) * (C + E) + 2.0f * rx
               + expf(-rq) * (D + F) + 2.0f * rq;
    }
}

extern "C" void kernel_launch(void* const* d_in, const int* in_sizes, int n_in,
                              void* d_out, int out_size, void* d_ws, size_t ws_size,
                              hipStream_t stream) {
    const float* pred = (const float*)d_in[0];
    const float* targ = (const float*)d_in[1];
    const float* imu  = (const float*)d_in[2];
    const float* sax  = (const float*)d_in[3];
    const float* saq  = (const float*)d_in[4];
    const float* srx  = (const float*)d_in[5];
    const float* srq  = (const float*)d_in[6];
    float* out = (float*)d_out;
    float* partial = (float*)d_ws;   // NBLK * 6 floats ~= 100 KB

    loss_main<<<NBLK, BLOCK, 0, stream>>>(pred, targ, imu, partial);
    loss_finalize<<<1, 256, 0, stream>>>(partial, sax, saq, srx, srq, out);
}

// Round 6
// 205.247 us; speedup vs baseline: 1.0224x; 1.0056x over previous
//
#include <hip/hip_runtime.h>
#include <math.h>

#define NN 2048
#define TT 1024
#define EPSF 1e-8f

#define NPAIR  (NN * TT / 2)               // 1,048,576 row-pairs
#define BLOCK  256
#define WPB    (BLOCK / 64)                // 4 waves per block
#define NBATCH ((NPAIR + 62) / 63)         // 16,645 batches (63 pairs each)
#define NWAVE  ((NBATCH + 1) / 2)          // 8,323 waves (2 batches each)
#define NBLK   ((NWAVE + WPB - 1) / WPB)   // 2,081 blocks

struct Quat { float w, x, y, z; };

__device__ inline float fsqrt_f(float x) { return __builtin_amdgcn_sqrtf(x); }
__device__ inline float frcp_f(float x)  { return __builtin_amdgcn_rcpf(x); }

// max abs error ~6.8e-5 rad (Abramowitz-Stegun 4.4.45 + reflection)
__device__ inline float acos_fast(float x) {
    float ax = fabsf(x);
    float p = fmaf(ax, -0.0187293f, 0.0742610f);
    p = fmaf(ax, p, -0.2121144f);
    p = fmaf(ax, p, 1.5707288f);
    float r = fsqrt_f(1.0f - ax) * p;
    return x >= 0.0f ? r : 3.14159274f - r;
}

__device__ inline Quat qmul(const Quat a, const Quat b) {
    Quat r;
    r.w = a.w * b.w - a.x * b.x - a.y * b.y - a.z * b.z;
    r.x = a.w * b.x + a.x * b.w + a.y * b.z - a.z * b.y;
    r.y = a.w * b.y - a.x * b.z + a.y * b.w + a.z * b.x;
    r.z = a.w * b.z + a.x * b.y - a.y * b.x + a.z * b.w;
    return r;
}

__device__ inline Quat qconj(const Quat q) {
    Quat r; r.w = q.w; r.x = -q.x; r.y = -q.y; r.z = -q.z; return r;
}

__device__ inline Quat qexp3(float vx, float vy, float vz) {
    float ss = fmaf(vx, vx, fmaf(vy, vy, vz * vz));
    float n = fmaxf(fsqrt_f(ss), EPSF);
    float s = __sinf(n) * frcp_f(n);
    Quat r; r.w = __cosf(n); r.x = s * vx; r.y = s * vy; r.z = s * vz;
    return r;
}

__device__ inline void qlog3(const Quat q, float& ox, float& oy, float& oz) {
    float ss = fmaf(q.x, q.x, fmaf(q.y, q.y, q.z * q.z));
    float n = fmaxf(fsqrt_f(ss), EPSF);
    float c = fminf(fmaxf(q.w, -1.0f), 1.0f);
    float s = acos_fast(c) * frcp_f(n);
    ox = q.x * s; oy = q.y * s; oz = q.z * s;
}

__device__ inline float waveReduceF(float v) {
    #pragma unroll
    for (int o = 32; o > 0; o >>= 1) v += __shfl_down(v, o);
    return v;
}

__device__ inline double waveReduceD(double v) {
    #pragma unroll
    for (int o = 32; o > 0; o >>= 1) v += __shfl_down(v, o);
    return v;
}

// imu_ori_shift = qlog(qmult(qinv(q0), qmult(q0, dq))) = qlog(dq) = 0.5*dt*w
// exactly (q0 unit), so the dq sin/cos chain collapses to one multiply.
__device__ inline void pair_terms(
    const float* pa, const float* pb, const float* ga, const float* gb,
    const Quat qR, const Quat qN,
    float a0, float a1, float a2, float v0, float v1, float v2,
    float w0, float w1, float w2, float ts0, float ts1,
    float& s2, float& s3, float& s4, float& s5)
{
    float pv0 = pb[0] - pa[0], pv1 = pb[1] - pa[1], pv2 = pb[2] - pa[2];
    float pv3 = pb[3] - pa[3], pv4 = pb[4] - pa[4], pv5 = pb[5] - pa[5];
    float tv0 = gb[0] - ga[0], tv1 = gb[1] - ga[1], tv2 = gb[2] - ga[2];
    float tv3 = gb[3] - ga[3], tv4 = gb[4] - ga[4], tv5 = gb[5] - ga[5];

    s2 += fabsf(pv0 - tv0) + fabsf(pv1 - tv1) + fabsf(pv2 - tv2);
    s3 += fabsf(pv3 - tv3) + fabsf(pv4 - tv4) + fabsf(pv5 - tv5);

    Quat r01 = qmul(qconj(qR), qN);
    float tq0, tq1, tq2;
    qlog3(r01, tq0, tq1, tq2);            // targ_imu_q

    float dt = (ts1 - ts0) * 1e-9f;
    float hdt2 = 0.5f * dt * dt;
    float it0 = fmaf(v0, dt, a0 * hdt2);
    float it1 = fmaf(v1, dt, a1 * hdt2);
    float it2 = fmaf(v2, dt, a2 * hdt2);
    s4 += fabsf(pv0 - it0) + fabsf(pv1 - it1) + fabsf(pv2 - it2);

    float kk = 0.5f * dt;                 // imu_ori_shift = kk * w
    s5 += fabsf(tq0 - kk * w0) + fabsf(tq1 - kk * w1) + fabsf(tq2 - kk * w2);
}

struct PB {
    float4 P0, P1, P2, G0, G1, G2, I0, I1, I2, I3, I4;
};

__device__ inline PB load_pair(const float* __restrict__ pred,
                               const float* __restrict__ targ,
                               const float* __restrict__ imu, long u)
{
    const float4* p4 = reinterpret_cast<const float4*>(pred) + u * 3;
    const float4* g4 = reinterpret_cast<const float4*>(targ) + u * 3;
    const float4* i4 = reinterpret_cast<const float4*>(imu)  + u * 5;
    PB d;
    d.P0 = p4[0]; d.P1 = p4[1]; d.P2 = p4[2];
    d.G0 = g4[0]; d.G1 = g4[1]; d.G2 = g4[2];
    d.I0 = i4[0]; d.I1 = i4[1]; d.I2 = i4[2]; d.I3 = i4[3]; d.I4 = i4[4];
    return d;
}

__device__ inline void process_batch(const PB& d, long u, bool active,
    float& s0, float& s1, float& s2, float& s3, float& s4, float& s5)
{
    float pA[6] = {d.P0.x, d.P0.y, d.P0.z, d.P0.w, d.P1.x, d.P1.y};
    float pB_[6]= {d.P1.z, d.P1.w, d.P2.x, d.P2.y, d.P2.z, d.P2.w};
    float gA[6] = {d.G0.x, d.G0.y, d.G0.z, d.G0.w, d.G1.x, d.G1.y};
    float gB[6] = {d.G1.z, d.G1.w, d.G2.x, d.G2.y, d.G2.z, d.G2.w};

    Quat qA = qexp3(gA[3], gA[4], gA[5]);
    Quat qB = qexp3(gB[3], gB[4], gB[5]);
    float tsA = d.I2.y, tsB = d.I4.w;

    // C row (next pair's A row) via in-register shuffle from lane+1
    float pC[6], gC[6];
    #pragma unroll
    for (int j = 0; j < 6; ++j) {
        pC[j] = __shfl_down(pA[j], 1);
        gC[j] = __shfl_down(gA[j], 1);
    }
    float tsC = __shfl_down(tsA, 1);
    Quat qC;
    qC.w = __shfl_down(qA.w, 1); qC.x = __shfl_down(qA.x, 1);
    qC.y = __shfl_down(qA.y, 1); qC.z = __shfl_down(qA.z, 1);

    if (active) {
        s0 += fabsf(pA[0]-gA[0]) + fabsf(pA[1]-gA[1]) + fabsf(pA[2]-gA[2])
            + fabsf(pB_[0]-gB[0]) + fabsf(pB_[1]-gB[1]) + fabsf(pB_[2]-gB[2]);
        s1 += fabsf(pA[3]-gA[3]) + fabsf(pA[4]-gA[4]) + fabsf(pA[5]-gA[5])
            + fabsf(pB_[3]-gB[3]) + fabsf(pB_[4]-gB[4]) + fabsf(pB_[5]-gB[5]);

        pair_terms(pA, pB_, gA, gB, qA, qB,
                   d.I0.x, d.I0.y, d.I0.z,
                   d.I0.w, d.I1.x, d.I1.y,
                   d.I1.z, d.I1.w, d.I2.x,
                   tsA, tsB, s2, s3, s4, s5);

        if ((u & 511) != 511) {            // not last pair of its sequence
            pair_terms(pB_, pC, gB, gC, qB, qC,
                       d.I2.z, d.I2.w, d.I3.x,
                       d.I3.y, d.I3.z, d.I3.w,
                       d.I4.x, d.I4.y, d.I4.z,
                       tsB, tsC, s2, s3, s4, s5);
        }
    }
}

__global__ __launch_bounds__(BLOCK, 2) void loss_main(
    const float* __restrict__ pred, const float* __restrict__ targ,
    const float* __restrict__ imu, float* __restrict__ partial)
{
    const int tid  = threadIdx.x;
    const int lane = tid & 63;
    const int wid  = tid >> 6;

    const long wave = (long)blockIdx.x * WPB + wid;
    const long u0 = (2 * wave)     * 63 + lane;
    const long u1 = (2 * wave + 1) * 63 + lane;
    const bool act0 = (lane < 63) && (u0 < NPAIR);
    const bool act1 = (lane < 63) && (u1 < NPAIR);
    const long uc0 = u0 < NPAIR ? u0 : (NPAIR - 1);
    const long uc1 = u1 < NPAIR ? u1 : (NPAIR - 1);

    // issue BOTH batches' loads (22 independent float4) before any use;
    // sched_barrier(0) pins them above the compute so the memory queue
    // stays full while batch-0 compute runs.
    PB d0 = load_pair(pred, targ, imu, uc0);
    PB d1 = load_pair(pred, targ, imu, uc1);
    __builtin_amdgcn_sched_barrier(0);

    float s0 = 0.f, s1 = 0.f, s2 = 0.f, s3 = 0.f, s4 = 0.f, s5 = 0.f;
    process_batch(d0, u0, act0, s0, s1, s2, s3, s4, s5);
    process_batch(d1, u1, act1, s0, s1, s2, s3, s4, s5);

    // block reduction: wave shuffle -> LDS -> per-block partial store
    s0 = waveReduceF(s0); s1 = waveReduceF(s1); s2 = waveReduceF(s2);
    s3 = waveReduceF(s3); s4 = waveReduceF(s4); s5 = waveReduceF(s5);

    __shared__ float red[WPB][6];
    if (lane == 0) {
        red[wid][0] = s0; red[wid][1] = s1; red[wid][2] = s2;
        red[wid][3] = s3; red[wid][4] = s4; red[wid][5] = s5;
    }
    __syncthreads();
    if (tid < 6) {
        const int c = tid;
        partial[(size_t)blockIdx.x * 6 + c] = red[0][c] + red[1][c] + red[2][c] + red[3][c];
    }
}

__global__ __launch_bounds__(256) void loss_finalize(
    const float* __restrict__ partial,
    const float* __restrict__ sax, const float* __restrict__ saq,
    const float* __restrict__ srx, const float* __restrict__ srq,
    float* __restrict__ out)
{
    double t0 = 0, t1 = 0, t2 = 0, t3 = 0, t4 = 0, t5 = 0;
    for (int r = threadIdx.x; r < NBLK; r += 256) {
        const float* p = partial + (size_t)r * 6;
        t0 += p[0]; t1 += p[1]; t2 += p[2];
        t3 += p[3]; t4 += p[4]; t5 += p[5];
    }
    t0 = waveReduceD(t0); t1 = waveReduceD(t1); t2 = waveReduceD(t2);
    t3 = waveReduceD(t3); t4 = waveReduceD(t4); t5 = waveReduceD(t5);

    __shared__ double red[4][6];
    const int lane = threadIdx.x & 63;
    const int wid  = threadIdx.x >> 6;
    if (lane == 0) {
        red[wid][0] = t0; red[wid][1] = t1; red[wid][2] = t2;
        red[wid][3] = t3; red[wid][4] = t4; red[wid][5] = t5;
    }
    __syncthreads();
    if (threadIdx.x == 0) {
        double a0 = 0, a1 = 0, a2 = 0, a3 = 0, a4 = 0, a5 = 0;
        #pragma unroll
        for (int w = 0; w < 4; ++w) {
            a0 += red[w][0]; a1 += red[w][1]; a2 += red[w][2];
            a3 += red[w][3]; a4 += red[w][4]; a5 += red[w][5];
        }
        const double inv_abs = 1.0 / ((double)NN * TT * 3);
        const double inv_vo  = 1.0 / ((double)NN * (TT - 1) * 3);
        float A = (float)(a0 * inv_abs);
        float B = (float)(a1 * inv_abs);
        float C = (float)(a2 * inv_vo);
        float D = (float)(a3 * inv_vo);
        float E = (float)(a4 * inv_vo);
        float F = (float)(a5 * inv_vo);
        float sx = sax[0], sq = saq[0], rx = srx[0], rq = srq[0];
        out[0] = expf(-sx) * A + sx + expf(-sq) * B + sq
               + expf(-rx) * (C + E) + 2.0f * rx
               + expf(-rq) * (D + F) + 2.0f * rq;
    }
}

extern "C" void kernel_launch(void* const* d_in, const int* in_sizes, int n_in,
                              void* d_out, int out_size, void* d_ws, size_t ws_size,
                              hipStream_t stream) {
    const float* pred = (const float*)d_in[0];
    const float* targ = (const float*)d_in[1];
    const float* imu  = (const float*)d_in[2];
    const float* sax  = (const float*)d_in[3];
    const float* saq  = (const float*)d_in[4];
    const float* srx  = (const float*)d_in[5];
    const float* srq  = (const float*)d_in[6];
    float* out = (float*)d_out;
    float* partial = (float*)d_ws;   // NBLK * 6 floats ~= 50 KB

    loss_main<<<NBLK, BLOCK, 0, stream>>>(pred, targ, imu, partial);
    loss_finalize<<<1, 256, 0, stream>>>(partial, sax, saq, srx, srq, out);
}